// Round 7
// baseline (85.058 us; speedup 1.0000x reference)
//
#include <hip/hip_runtime.h>
#include <hip/hip_bf16.h>
#include <math.h>

// Problem constants
#define BB   256
#define INW  512
#define HH   1024
#define OUTW 512
#define SS   512
#define WD   256
#define P_READ  262
#define P_WRITE 774
#define RW_LD   1056   // 272 (read pad) + 784 (write pad)
#define W_OFF   272

typedef __attribute__((ext_vector_type(8))) short bf16x8;
typedef __attribute__((ext_vector_type(4))) float f32x4;

__device__ __forceinline__ float sigmoidf(float x) { return 1.f / (1.f + expf(-x)); }
__device__ __forceinline__ float softplusf(float x) { return (x > 20.f) ? x : log1pf(expf(x)); }
__device__ __forceinline__ unsigned short f2b(float f) {
    union { float f; unsigned u; } c; c.f = f;
    return (unsigned short)((c.u + 0x7FFFu + ((c.u >> 16) & 1u)) >> 16);
}
__device__ __forceinline__ void st_bf4(__hip_bfloat16* d, float a, float b, float c, float e) {
    ushort4 u; u.x = f2b(a); u.y = f2b(b); u.z = f2b(c); u.w = f2b(e);
    *reinterpret_cast<ushort4*>(d) = u;
}
__device__ __forceinline__ float wave_sum(float v) {
    #pragma unroll
    for (int off = 32; off > 0; off >>= 1) v += __shfl_down(v, off, 64);
    return v;
}
__device__ __forceinline__ float wave_bsum(float v) {   // butterfly: all lanes get result
    #pragma unroll
    for (int off = 1; off < 64; off <<= 1) v += __shfl_xor(v, off, 64);
    return v;
}
__device__ __forceinline__ float wave_bmax(float v) {
    #pragma unroll
    for (int off = 1; off < 64; off <<= 1) v = fmaxf(v, __shfl_xor(v, off, 64));
    return v;
}

// conversion segment sizes (all multiples of 4)
#define N_WIH (3072*512)
#define N_WRW (RW_LD*1024)
#define N_WO  (512*1280)
#define N_X   (256*512)
#define N_MB  (512*256)
#define N_MT  (256*512)
#define N_BIA 3072
#define N_BRW RW_LD
#define N_TOT (N_WIH+N_WRW+N_WO+N_X+N_MB+N_MT+N_BIA+N_BRW)
#define NB_CVT ((N_TOT/4 + 255) / 256)

// ================= K1: convert/pack (4-wide) + mem norms + biases =================
__global__ __launch_bounds__(256)
void convert_all(const float* __restrict__ W_ih, const float* __restrict__ b_ih,
                 const float* __restrict__ b_hh,
                 const float* __restrict__ W_read, const float* __restrict__ b_read,
                 const float* __restrict__ W_write, const float* __restrict__ b_write,
                 const float* __restrict__ W_out, const float* __restrict__ x,
                 const float* __restrict__ mem,
                 __hip_bfloat16* __restrict__ Wih_c, __hip_bfloat16* __restrict__ Wrw_p,
                 __hip_bfloat16* __restrict__ Wo_b, __hip_bfloat16* __restrict__ x_b,
                 __hip_bfloat16* __restrict__ mem_b, __hip_bfloat16* __restrict__ memT_b,
                 float* __restrict__ bias_c, float* __restrict__ bias_rw,
                 float* __restrict__ mem_norm)
{
    if (blockIdx.x >= NB_CVT) {
        __shared__ float red[4];
        int s = blockIdx.x - NB_CVT;
        float v = mem[(size_t)s * WD + threadIdx.x];
        float vv = wave_sum(v * v);
        if ((threadIdx.x & 63) == 0) red[threadIdx.x >> 6] = vv;
        __syncthreads();
        if (threadIdx.x == 0)
            mem_norm[s] = fmaxf(sqrtf(red[0] + red[1] + red[2] + red[3]), 1e-8f);
        return;
    }
    long i = ((long)blockIdx.x * 256 + threadIdx.x) * 4;
    if (i >= N_TOT) return;
    if (i < N_WIH) {
        int r = (int)(i >> 9), c = (int)(i & 511);
        int sr = r < 1024 ? r : r + 1024;    // skip f-gate rows
        float4 v = *reinterpret_cast<const float4*>(W_ih + (size_t)sr * 768 + c);
        st_bf4(Wih_c + i, v.x, v.y, v.z, v.w);
        return;
    }
    i -= N_WIH;
    if (i < N_WRW) {
        int r = (int)(i >> 10), c = (int)(i & 1023);
        float4 v = make_float4(0.f, 0.f, 0.f, 0.f);
        if (r < W_OFF) { if (r < P_READ) v = *reinterpret_cast<const float4*>(W_read + (size_t)r * 1024 + c); }
        else { int wr = r - W_OFF; if (wr < P_WRITE) v = *reinterpret_cast<const float4*>(W_write + (size_t)wr * 1024 + c); }
        st_bf4(Wrw_p + i, v.x, v.y, v.z, v.w);
        return;
    }
    i -= N_WRW;
    if (i < N_WO) {
        float4 v = *reinterpret_cast<const float4*>(W_out + i);
        st_bf4(Wo_b + i, v.x, v.y, v.z, v.w);
        return;
    }
    i -= N_WO;
    if (i < N_X) {
        float4 v = *reinterpret_cast<const float4*>(x + i);
        st_bf4(x_b + i, v.x, v.y, v.z, v.w);
        return;
    }
    i -= N_X;
    if (i < N_MB) {
        float4 v = *reinterpret_cast<const float4*>(mem + i);
        st_bf4(mem_b + i, v.x, v.y, v.z, v.w);
        return;
    }
    i -= N_MB;
    if (i < N_MT) {   // transpose gather (L2-resident source)
        int w = (int)(i >> 9), s = (int)(i & 511);
        st_bf4(memT_b + i, mem[(size_t)s * 256 + w], mem[(size_t)(s + 1) * 256 + w],
               mem[(size_t)(s + 2) * 256 + w], mem[(size_t)(s + 3) * 256 + w]);
        return;
    }
    i -= N_MT;
    if (i < N_BIA) {
        #pragma unroll
        for (int u = 0; u < 4; ++u) {
            long r = i + u;
            long sr = r < 1024 ? r : r + 1024;
            bias_c[r] = b_ih[sr] + b_hh[sr];
        }
        return;
    }
    i -= N_BIA;
    {
        #pragma unroll
        for (int u = 0; u < 4; ++u) {
            long r = i + u;
            float v = 0.f;
            if (r < W_OFF) { if (r < P_READ) v = b_read[r]; }
            else { long wr = r - W_OFF; if (wr < P_WRITE) v = b_write[wr]; }
            bias_rw[r] = v;
        }
    }
}

// ================= K2: gates GEMM + LSTM -> h_b [256][1024] bf16 =================
__global__ __launch_bounds__(64)
void gemm_gates(const __hip_bfloat16* __restrict__ x_b,
                const __hip_bfloat16* __restrict__ Wih_c,
                const float* __restrict__ bias_c,
                __hip_bfloat16* __restrict__ h_b)
{
    const int l = threadIdx.x;
    const int bn = blockIdx.x * 16;
    const int bm = blockIdx.y * 16;
    const int r = l & 15, q = l >> 4;
    const __hip_bfloat16* ap = x_b + (size_t)(bm + r) * INW + q * 8;
    const __hip_bfloat16* bi = Wih_c + (size_t)(bn + r) * INW + q * 8;
    const __hip_bfloat16* bg = bi + (size_t)1024 * INW;
    const __hip_bfloat16* bo = bi + (size_t)2048 * INW;
    f32x4 ai = {0.f,0.f,0.f,0.f}, ag = ai, ao = ai;
    #pragma unroll
    for (int k = 0; k < INW; k += 32) {
        bf16x8 a = *reinterpret_cast<const bf16x8*>(ap + k);
        ai = __builtin_amdgcn_mfma_f32_16x16x32_bf16(a, *reinterpret_cast<const bf16x8*>(bi + k), ai, 0, 0, 0);
        ag = __builtin_amdgcn_mfma_f32_16x16x32_bf16(a, *reinterpret_cast<const bf16x8*>(bg + k), ag, 0, 0, 0);
        ao = __builtin_amdgcn_mfma_f32_16x16x32_bf16(a, *reinterpret_cast<const bf16x8*>(bo + k), ao, 0, 0, 0);
    }
    const int j = bn + r;
    const float bii = bias_c[j], big = bias_c[1024 + j], bio = bias_c[2048 + j];
    #pragma unroll
    for (int jj = 0; jj < 4; ++jj) {
        int b = bm + q * 4 + jj;
        float c = sigmoidf(ai[jj] + bii) * tanhf(ag[jj] + big);
        h_b[(size_t)b * HH + j] = __float2bfloat16(sigmoidf(ao[jj] + bio) * tanhf(c));
    }
}

// ================= K3: dual GEMM (rpwp + keys harvest || out h-part) =================
__global__ __launch_bounds__(64)
void gemm_dual(const __hip_bfloat16* __restrict__ h_b,
               const __hip_bfloat16* __restrict__ Wrw_p,
               const __hip_bfloat16* __restrict__ Wo_b,
               const float* __restrict__ bias_rw, const float* __restrict__ b_out,
               float* __restrict__ rpwp, float* __restrict__ out,
               __hip_bfloat16* __restrict__ keys)
{
    const int bid = blockIdx.x;
    const int lane = threadIdx.x;
    const int r = lane & 15, q = lane >> 4;
    int bm, bn, ldb;
    const __hip_bfloat16* B;
    if (bid < 1056) { int nt = bid % 66, mt = bid / 66; bm = mt * 16; bn = nt * 16; B = Wrw_p; ldb = HH; }
    else { int o = bid - 1056; int nt = o & 31, mt = o >> 5; bm = mt * 16; bn = nt * 16; B = Wo_b; ldb = 1280; }

    const __hip_bfloat16* ap = h_b + (size_t)(bm + r) * HH + q * 8;
    const __hip_bfloat16* bp = B + (size_t)(bn + r) * ldb + q * 8;
    f32x4 a0 = {0.f,0.f,0.f,0.f}, a1 = a0;
    #pragma unroll 8
    for (int k = 0; k < 512; k += 32) {
        a0 = __builtin_amdgcn_mfma_f32_16x16x32_bf16(
            *reinterpret_cast<const bf16x8*>(ap + k),
            *reinterpret_cast<const bf16x8*>(bp + k), a0, 0, 0, 0);
        a1 = __builtin_amdgcn_mfma_f32_16x16x32_bf16(
            *reinterpret_cast<const bf16x8*>(ap + 512 + k),
            *reinterpret_cast<const bf16x8*>(bp + 512 + k), a1, 0, 0, 0);
    }
    const int col = bn + r;
    if (bid < 1056) {
        const float bv = bias_rw[col];
        #pragma unroll
        for (int j = 0; j < 4; ++j) {
            int m = bm + q * 4 + j;
            float v = a0[j] + a1[j] + bv;
            rpwp[(size_t)m * RW_LD + col] = v;
            // interleaved keys: row 2m = read key, row 2m+1 = write key
            if (col < WD)
                keys[(size_t)(2 * m) * WD + col] = __float2bfloat16(v);
            else if (col >= W_OFF && col < W_OFF + WD)
                keys[(size_t)(2 * m + 1) * WD + (col - W_OFF)] = __float2bfloat16(v);
        }
    } else {
        const float bv = b_out[col];
        #pragma unroll
        for (int j = 0; j < 4; ++j) {
            int m = bm + q * 4 + j;
            out[(size_t)m * OUTW + col] = a0[j] + a1[j] + bv;
        }
    }
}

// ================= K4: addr_mega — num MFMA + addressing + t12 MFMA + rv + out_rv MFMA =================
// 32 blocks x 512 threads; block handles 8 batches (one wave per batch in scalar phases)
#define AB_BPB 8
__global__ __launch_bounds__(512)
void addr_mega(const float* __restrict__ rpwp, const float* __restrict__ mem_norm,
               const __hip_bfloat16* __restrict__ keys,
               const __hip_bfloat16* __restrict__ mem_b,
               const __hip_bfloat16* __restrict__ memT_b,
               const __hip_bfloat16* __restrict__ Wo_b,
               float* __restrict__ out)
{
    __shared__ float s_num[16][513];             // rows 2w=read num, 2w+1=write num; reused for gw
    __shared__ __hip_bfloat16 s_a12[16][520];    // rows 0-7 read_w, 8-15 read_w*write_w
    __shared__ float s_t12[16][257];             // rows 0-7 t1, 8-15 t2
    __shared__ __hip_bfloat16 s_rv[16][264];     // rows 0-7 rv, 8-15 zero

    const int t = threadIdx.x;
    const int lane = t & 63;
    const int w = t >> 6;                 // wave id 0..7
    const int B0 = blockIdx.x * AB_BPB;
    const int r = lane & 15, q = lane >> 4;

    // ---- phase 1: num strips [16 x 512] = keys_strip @ mem^T ----
    {
        const __hip_bfloat16* ap = keys + (size_t)(blockIdx.x * 16 + r) * WD + q * 8;
        for (int nt = w; nt < 32; nt += 8) {
            const __hip_bfloat16* bp = mem_b + (size_t)(nt * 16 + r) * WD + q * 8;
            f32x4 acc = {0.f,0.f,0.f,0.f};
            #pragma unroll
            for (int k = 0; k < WD; k += 32)
                acc = __builtin_amdgcn_mfma_f32_16x16x32_bf16(
                    *reinterpret_cast<const bf16x8*>(ap + k),
                    *reinterpret_cast<const bf16x8*>(bp + k), acc, 0, 0, 0);
            #pragma unroll
            for (int j = 0; j < 4; ++j)
                s_num[q * 4 + j][nt * 16 + r] = acc[j];
        }
    }
    __syncthreads();

    // ---- phase 2: addressing, one wave per batch ----
    float t3v;
    {
        const int b = B0 + w;
        const float* pr = rpwp + (size_t)b * RW_LD;
        const float* pw2 = pr + W_OFF;

        // key norms
        float s2r = 0.f, s2w = 0.f;
        #pragma unroll
        for (int c = 0; c < 4; ++c) {
            float vr = pr[lane + 64 * c];  s2r += vr * vr;
            float vw = pw2[lane + 64 * c]; s2w += vw * vw;
        }
        s2r = wave_bsum(s2r); s2w = wave_bsum(s2w);
        float knr = fmaxf(sqrtf(s2r), 1e-8f), knw = fmaxf(sqrtf(s2w), 1e-8f);

        // header params (broadcast loads)
        float beta_r = softplusf(pr[WD]);
        float gate_r = sigmoidf(pr[WD + 1]);
        float r0 = pr[WD+2], r1 = pr[WD+3], r2 = pr[WD+4];
        float rmx = fmaxf(r0, fmaxf(r1, r2));
        float re0 = expf(r0-rmx), re1 = expf(r1-rmx), re2 = expf(r2-rmx);
        float rinv = 1.f / (re0+re1+re2);
        float shr0 = re0*rinv, shr1 = re1*rinv, shr2 = re2*rinv;
        float gamma_r = 1.f + softplusf(pr[WD + 5]);

        float beta_w = softplusf(pw2[WD]);
        float gate_w = sigmoidf(pw2[WD + 1]);
        float w0 = pw2[WD+2], w1 = pw2[WD+3], w2 = pw2[WD+4];
        float wmx = fmaxf(w0, fmaxf(w1, w2));
        float we0 = expf(w0-wmx), we1 = expf(w1-wmx), we2 = expf(w2-wmx);
        float winv = 1.f / (we0+we1+we2);
        float shw0 = we0*winv, shw1 = we1*winv, shw2 = we2*winv;
        float gamma_w = 1.f + softplusf(pw2[WD + 5]);

        // sims (8 slots per lane), running max
        float er[8], ew[8];
        float mr = -1e30f, mw = -1e30f;
        #pragma unroll
        for (int c = 0; c < 8; ++c) {
            int s = lane + 64 * c;
            float inv = 1.f / mem_norm[s];
            er[c] = s_num[2*w][s]   * inv / knr * beta_r;
            ew[c] = s_num[2*w+1][s] * inv / knw * beta_w;
            mr = fmaxf(mr, er[c]); mw = fmaxf(mw, ew[c]);
        }
        mr = wave_bmax(mr); mw = wave_bmax(mw);
        float sr = 0.f, sw = 0.f;
        #pragma unroll
        for (int c = 0; c < 8; ++c) {
            er[c] = expf(er[c] - mr); sr += er[c];
            ew[c] = expf(ew[c] - mw); sw += ew[c];
        }
        sr = wave_bsum(sr); sw = wave_bsum(sw);
        float irn = 1.f / sr, iwn = 1.f / sw;

        // gate (prev_w = one-hot slot 0) -> gw into LDS rows (overwrite num)
        float gr[8], gw8[8];
        #pragma unroll
        for (int c = 0; c < 8; ++c) {
            int s = lane + 64 * c;
            float oh = (s == 0) ? 1.f : 0.f;
            gr[c]  = gate_r * er[c] * irn + (1.f - gate_r) * oh;
            gw8[c] = gate_w * ew[c] * iwn + (1.f - gate_w) * oh;
            s_num[2*w][s] = gr[c];
            s_num[2*w+1][s] = gw8[c];
        }
        // CRITICAL: cross-lane LDS visibility fence. Without this the compiler may
        // hoist the neighbor reads below above the writes above (per-thread they
        // are provably disjoint addresses) -> stale (signed) sims -> powf(neg) = NaN.
        __syncthreads();

        // shift + sharpen
        float ssr = 0.f, ssw = 0.f;
        float spr[8], spw[8];
        #pragma unroll
        for (int c = 0; c < 8; ++c) {
            int s = lane + 64 * c;
            int sm = (s + SS - 1) & (SS - 1), sp = (s + 1) & (SS - 1);
            float vr = shr0 * s_num[2*w][sm] + shr1 * gr[c]  + shr2 * s_num[2*w][sp];
            float vw = shw0 * s_num[2*w+1][sm] + shw1 * gw8[c] + shw2 * s_num[2*w+1][sp];
            spr[c] = powf(fmaxf(vr, 0.f), gamma_r); ssr += spr[c];
            spw[c] = powf(fmaxf(vw, 0.f), gamma_w); ssw += spw[c];
        }
        ssr = wave_bsum(ssr) + 1e-6f; ssw = wave_bsum(ssw) + 1e-6f;
        float nr2 = 1.f / ssr, nw2 = 1.f / ssw;
        float t3l = 0.f;
        #pragma unroll
        for (int c = 0; c < 8; ++c) {
            int s = lane + 64 * c;
            float rf = spr[c] * nr2;
            float pd = rf * (spw[c] * nw2);
            t3l += pd;
            s_a12[w][s]     = __float2bfloat16(rf);
            s_a12[8 + w][s] = __float2bfloat16(pd);
        }
        t3v = wave_bsum(t3l);
    }
    __syncthreads();

    // ---- phase 3: t12 [16 x 256] = s_a12 @ memT^T ----
    {
        for (int nt = w; nt < 16; nt += 8) {
            const __hip_bfloat16* bp = memT_b + (size_t)(nt * 16 + r) * SS + q * 8;
            f32x4 acc = {0.f,0.f,0.f,0.f};
            #pragma unroll
            for (int k = 0; k < SS; k += 32)
                acc = __builtin_amdgcn_mfma_f32_16x16x32_bf16(
                    *reinterpret_cast<const bf16x8*>(&s_a12[r][k + q * 8]),
                    *reinterpret_cast<const bf16x8*>(bp + k), acc, 0, 0, 0);
            #pragma unroll
            for (int j = 0; j < 4; ++j)
                s_t12[q * 4 + j][nt * 16 + r] = acc[j];
        }
    }
    __syncthreads();

    // ---- phase 4: rv = t1 - e*t2 + a*t3 (wave per batch) ----
    {
        const int b = B0 + w;
        const float* pw2 = rpwp + (size_t)b * RW_LD + W_OFF;
        #pragma unroll
        for (int c = 0; c < 4; ++c) {
            int col = lane + 64 * c;
            float t1 = s_t12[w][col], t2 = s_t12[8 + w][col];
            float e = sigmoidf(pw2[P_READ + col]);
            float a = tanhf(pw2[P_READ + WD + col]);
            s_rv[w][col]     = __float2bfloat16(t1 - e * t2 + a * t3v);
            s_rv[8 + w][col] = __float2bfloat16(0.f);
        }
    }
    __syncthreads();

    // ---- phase 5: out_rv [8 x 512] += s_rv @ Wo_rv^T ----
    {
        for (int nt = w; nt < 32; nt += 8) {
            const __hip_bfloat16* bp = Wo_b + (size_t)(nt * 16 + r) * 1280 + 1024 + q * 8;
            f32x4 acc = {0.f,0.f,0.f,0.f};
            #pragma unroll
            for (int k = 0; k < WD; k += 32)
                acc = __builtin_amdgcn_mfma_f32_16x16x32_bf16(
                    *reinterpret_cast<const bf16x8*>(&s_rv[r][k + q * 8]),
                    *reinterpret_cast<const bf16x8*>(bp + k), acc, 0, 0, 0);
            int col = nt * 16 + r;
            #pragma unroll
            for (int j = 0; j < 4; ++j) {
                int m = q * 4 + j;
                if (m < AB_BPB)
                    out[(size_t)(B0 + m) * OUTW + col] += acc[j];
            }
        }
    }
}

// ---------------- host launcher ----------------
extern "C" void kernel_launch(void* const* d_in, const int* in_sizes, int n_in,
                              void* d_out, int out_size, void* d_ws, size_t ws_size,
                              hipStream_t stream)
{
    const float* x       = (const float*)d_in[0];
    const float* W_ih    = (const float*)d_in[1];
    const float* b_ih    = (const float*)d_in[2];
    const float* b_hh    = (const float*)d_in[4];
    const float* W_read  = (const float*)d_in[5];
    const float* b_read  = (const float*)d_in[6];
    const float* W_write = (const float*)d_in[7];
    const float* b_write = (const float*)d_in[8];
    const float* W_out   = (const float*)d_in[9];
    const float* b_out   = (const float*)d_in[10];
    const float* mem     = (const float*)d_in[11];

    float* ws = (float*)d_ws;
    float* rpwp     = ws;                 // 270336
    float* bias_c   = ws + 270336;        // 3072
    float* bias_rw  = ws + 273408;        // 1056
    float* mem_norm = ws + 274464;        // 512
    __hip_bfloat16* bfb = (__hip_bfloat16*)(ws + 274976);
    __hip_bfloat16* x_b    = bfb;                 // 131072
    __hip_bfloat16* Wih_c  = bfb + 131072;        // 1572864
    __hip_bfloat16* Wrw_p  = bfb + 1703936;       // 1081344
    __hip_bfloat16* Wo_b   = bfb + 2785280;       // 655360
    __hip_bfloat16* mem_b  = bfb + 3440640;       // 131072
    __hip_bfloat16* memT_b = bfb + 3571712;       // 131072
    __hip_bfloat16* h_b    = bfb + 3702784;       // 262144
    __hip_bfloat16* keys   = bfb + 3964928;       // 131072 (rows 2b / 2b+1)
    float* out = (float*)d_out;

    // K1: convert/pack + mem norms + biases
    convert_all<<<NB_CVT + SS, 256, 0, stream>>>(
        W_ih, b_ih, b_hh, W_read, b_read, W_write, b_write, W_out, x, mem,
        Wih_c, Wrw_p, Wo_b, x_b, mem_b, memT_b, bias_c, bias_rw, mem_norm);
    // K2: gates GEMM + LSTM -> h_b
    gemm_gates<<<dim3(64, 16), 64, 0, stream>>>(x_b, Wih_c, bias_c, h_b);
    // K3: rpwp GEMM (+keys harvest) || out h-part GEMM
    gemm_dual<<<1568, 64, 0, stream>>>(h_b, Wrw_p, Wo_b, bias_rw, b_out, rpwp, out, keys);
    // K4: addressing + rv + out rv-part (all MFMA-tiled)
    addr_mega<<<32, 512, 0, stream>>>(rpwp, mem_norm, keys, mem_b, memT_b, Wo_b, out);
}

// Round 8
// 80.224 us; speedup vs baseline: 1.0603x; 1.0603x over previous
//
#include <hip/hip_runtime.h>
#include <hip/hip_bf16.h>
#include <math.h>

// Problem constants
#define BB   256
#define INW  512
#define HH   1024
#define OUTW 512
#define SS   512
#define WD   256
#define P_READ  262
#define P_WRITE 774
#define RW_LD   1056   // 272 (read pad) + 784 (write pad)
#define W_OFF   272

typedef __attribute__((ext_vector_type(8))) short bf16x8;
typedef __attribute__((ext_vector_type(4))) float f32x4;

__device__ __forceinline__ float sigmoidf(float x) { return 1.f / (1.f + expf(-x)); }
__device__ __forceinline__ float softplusf(float x) { return (x > 20.f) ? x : log1pf(expf(x)); }
__device__ __forceinline__ unsigned short f2b(float f) {
    union { float f; unsigned u; } c; c.f = f;
    return (unsigned short)((c.u + 0x7FFFu + ((c.u >> 16) & 1u)) >> 16);
}
__device__ __forceinline__ void st_bf4(__hip_bfloat16* d, float a, float b, float c, float e) {
    ushort4 u; u.x = f2b(a); u.y = f2b(b); u.z = f2b(c); u.w = f2b(e);
    *reinterpret_cast<ushort4*>(d) = u;
}
__device__ __forceinline__ float wave_sum(float v) {
    #pragma unroll
    for (int off = 32; off > 0; off >>= 1) v += __shfl_down(v, off, 64);
    return v;
}
__device__ __forceinline__ float wave_bsum(float v) {   // butterfly: all lanes get result
    #pragma unroll
    for (int off = 1; off < 64; off <<= 1) v += __shfl_xor(v, off, 64);
    return v;
}
__device__ __forceinline__ float wave_bmax(float v) {
    #pragma unroll
    for (int off = 1; off < 64; off <<= 1) v = fmaxf(v, __shfl_xor(v, off, 64));
    return v;
}

// conversion segment sizes (all multiples of 4)
#define N_WIH (3072*512)
#define N_WRW (RW_LD*1024)
#define N_WO  (512*1280)
#define N_X   (256*512)
#define N_MB  (512*256)
#define N_MT  (256*512)
#define N_BIA 3072
#define N_BRW RW_LD
#define N_KP  (8*256)     // keys zero-pad rows 512..519
#define N_TOT (N_WIH+N_WRW+N_WO+N_X+N_MB+N_MT+N_BIA+N_BRW+N_KP)
#define NB_CVT ((N_TOT/4 + 255) / 256)

// ================= K1: convert/pack (4-wide) + mem norms + biases + keys pad =================
__global__ __launch_bounds__(256)
void convert_all(const float* __restrict__ W_ih, const float* __restrict__ b_ih,
                 const float* __restrict__ b_hh,
                 const float* __restrict__ W_read, const float* __restrict__ b_read,
                 const float* __restrict__ W_write, const float* __restrict__ b_write,
                 const float* __restrict__ W_out, const float* __restrict__ x,
                 const float* __restrict__ mem,
                 __hip_bfloat16* __restrict__ Wih_c, __hip_bfloat16* __restrict__ Wrw_p,
                 __hip_bfloat16* __restrict__ Wo_b, __hip_bfloat16* __restrict__ x_b,
                 __hip_bfloat16* __restrict__ mem_b, __hip_bfloat16* __restrict__ memT_b,
                 float* __restrict__ bias_c, float* __restrict__ bias_rw,
                 float* __restrict__ mem_norm, __hip_bfloat16* __restrict__ keys)
{
    if (blockIdx.x >= NB_CVT) {
        __shared__ float red[4];
        int s = blockIdx.x - NB_CVT;
        float v = mem[(size_t)s * WD + threadIdx.x];
        float vv = wave_sum(v * v);
        if ((threadIdx.x & 63) == 0) red[threadIdx.x >> 6] = vv;
        __syncthreads();
        if (threadIdx.x == 0)
            mem_norm[s] = fmaxf(sqrtf(red[0] + red[1] + red[2] + red[3]), 1e-8f);
        return;
    }
    long i = ((long)blockIdx.x * 256 + threadIdx.x) * 4;
    if (i >= N_TOT) return;
    if (i < N_WIH) {
        int r = (int)(i >> 9), c = (int)(i & 511);
        int sr = r < 1024 ? r : r + 1024;    // skip f-gate rows
        float4 v = *reinterpret_cast<const float4*>(W_ih + (size_t)sr * 768 + c);
        st_bf4(Wih_c + i, v.x, v.y, v.z, v.w);
        return;
    }
    i -= N_WIH;
    if (i < N_WRW) {
        int r = (int)(i >> 10), c = (int)(i & 1023);
        float4 v = make_float4(0.f, 0.f, 0.f, 0.f);
        if (r < W_OFF) { if (r < P_READ) v = *reinterpret_cast<const float4*>(W_read + (size_t)r * 1024 + c); }
        else { int wr = r - W_OFF; if (wr < P_WRITE) v = *reinterpret_cast<const float4*>(W_write + (size_t)wr * 1024 + c); }
        st_bf4(Wrw_p + i, v.x, v.y, v.z, v.w);
        return;
    }
    i -= N_WRW;
    if (i < N_WO) {
        float4 v = *reinterpret_cast<const float4*>(W_out + i);
        st_bf4(Wo_b + i, v.x, v.y, v.z, v.w);
        return;
    }
    i -= N_WO;
    if (i < N_X) {
        float4 v = *reinterpret_cast<const float4*>(x + i);
        st_bf4(x_b + i, v.x, v.y, v.z, v.w);
        return;
    }
    i -= N_X;
    if (i < N_MB) {
        float4 v = *reinterpret_cast<const float4*>(mem + i);
        st_bf4(mem_b + i, v.x, v.y, v.z, v.w);
        return;
    }
    i -= N_MB;
    if (i < N_MT) {   // transpose gather (L2-resident source)
        int w = (int)(i >> 9), s = (int)(i & 511);
        st_bf4(memT_b + i, mem[(size_t)s * 256 + w], mem[(size_t)(s + 1) * 256 + w],
               mem[(size_t)(s + 2) * 256 + w], mem[(size_t)(s + 3) * 256 + w]);
        return;
    }
    i -= N_MT;
    if (i < N_BIA) {
        #pragma unroll
        for (int u = 0; u < 4; ++u) {
            long r = i + u;
            long sr = r < 1024 ? r : r + 1024;
            bias_c[r] = b_ih[sr] + b_hh[sr];
        }
        return;
    }
    i -= N_BIA;
    if (i < N_BRW) {
        #pragma unroll
        for (int u = 0; u < 4; ++u) {
            long r = i + u;
            float v = 0.f;
            if (r < W_OFF) { if (r < P_READ) v = b_read[r]; }
            else { long wr = r - W_OFF; if (wr < P_WRITE) v = b_write[wr]; }
            bias_rw[r] = v;
        }
        return;
    }
    i -= N_BRW;
    st_bf4(keys + (size_t)512 * WD + i, 0.f, 0.f, 0.f, 0.f);   // pad rows 512..519
}

// ================= K2: gates GEMM + LSTM -> h_b [256][1024] bf16 =================
__global__ __launch_bounds__(64)
void gemm_gates(const __hip_bfloat16* __restrict__ x_b,
                const __hip_bfloat16* __restrict__ Wih_c,
                const float* __restrict__ bias_c,
                __hip_bfloat16* __restrict__ h_b)
{
    const int l = threadIdx.x;
    const int bn = blockIdx.x * 16;
    const int bm = blockIdx.y * 16;
    const int r = l & 15, q = l >> 4;
    const __hip_bfloat16* ap = x_b + (size_t)(bm + r) * INW + q * 8;
    const __hip_bfloat16* bi = Wih_c + (size_t)(bn + r) * INW + q * 8;
    const __hip_bfloat16* bg = bi + (size_t)1024 * INW;
    const __hip_bfloat16* bo = bi + (size_t)2048 * INW;
    f32x4 ai = {0.f,0.f,0.f,0.f}, ag = ai, ao = ai;
    #pragma unroll
    for (int k = 0; k < INW; k += 32) {
        bf16x8 a = *reinterpret_cast<const bf16x8*>(ap + k);
        ai = __builtin_amdgcn_mfma_f32_16x16x32_bf16(a, *reinterpret_cast<const bf16x8*>(bi + k), ai, 0, 0, 0);
        ag = __builtin_amdgcn_mfma_f32_16x16x32_bf16(a, *reinterpret_cast<const bf16x8*>(bg + k), ag, 0, 0, 0);
        ao = __builtin_amdgcn_mfma_f32_16x16x32_bf16(a, *reinterpret_cast<const bf16x8*>(bo + k), ao, 0, 0, 0);
    }
    const int j = bn + r;
    const float bii = bias_c[j], big = bias_c[1024 + j], bio = bias_c[2048 + j];
    #pragma unroll
    for (int jj = 0; jj < 4; ++jj) {
        int b = bm + q * 4 + jj;
        float c = sigmoidf(ai[jj] + bii) * tanhf(ag[jj] + big);
        h_b[(size_t)b * HH + j] = __float2bfloat16(sigmoidf(ao[jj] + bio) * tanhf(c));
    }
}

// ================= K3: dual GEMM (rpwp + keys harvest || out h-part) =================
__global__ __launch_bounds__(64)
void gemm_dual(const __hip_bfloat16* __restrict__ h_b,
               const __hip_bfloat16* __restrict__ Wrw_p,
               const __hip_bfloat16* __restrict__ Wo_b,
               const float* __restrict__ bias_rw, const float* __restrict__ b_out,
               float* __restrict__ rpwp, float* __restrict__ out,
               __hip_bfloat16* __restrict__ keys)
{
    const int bid = blockIdx.x;
    const int lane = threadIdx.x;
    const int r = lane & 15, q = lane >> 4;
    int bm, bn, ldb;
    const __hip_bfloat16* B;
    if (bid < 1056) { int nt = bid % 66, mt = bid / 66; bm = mt * 16; bn = nt * 16; B = Wrw_p; ldb = HH; }
    else { int o = bid - 1056; int nt = o & 31, mt = o >> 5; bm = mt * 16; bn = nt * 16; B = Wo_b; ldb = 1280; }

    const __hip_bfloat16* ap = h_b + (size_t)(bm + r) * HH + q * 8;
    const __hip_bfloat16* bp = B + (size_t)(bn + r) * ldb + q * 8;
    f32x4 a0 = {0.f,0.f,0.f,0.f}, a1 = a0;
    #pragma unroll 8
    for (int k = 0; k < 512; k += 32) {
        a0 = __builtin_amdgcn_mfma_f32_16x16x32_bf16(
            *reinterpret_cast<const bf16x8*>(ap + k),
            *reinterpret_cast<const bf16x8*>(bp + k), a0, 0, 0, 0);
        a1 = __builtin_amdgcn_mfma_f32_16x16x32_bf16(
            *reinterpret_cast<const bf16x8*>(ap + 512 + k),
            *reinterpret_cast<const bf16x8*>(bp + 512 + k), a1, 0, 0, 0);
    }
    const int col = bn + r;
    if (bid < 1056) {
        const float bv = bias_rw[col];
        #pragma unroll
        for (int j = 0; j < 4; ++j) {
            int m = bm + q * 4 + j;
            float v = a0[j] + a1[j] + bv;
            rpwp[(size_t)m * RW_LD + col] = v;
            // interleaved keys: row 2m = read key, row 2m+1 = write key
            if (col < WD)
                keys[(size_t)(2 * m) * WD + col] = __float2bfloat16(v);
            else if (col >= W_OFF && col < W_OFF + WD)
                keys[(size_t)(2 * m + 1) * WD + (col - W_OFF)] = __float2bfloat16(v);
        }
    } else {
        const float bv = b_out[col];
        #pragma unroll
        for (int j = 0; j < 4; ++j) {
            int m = bm + q * 4 + j;
            out[(size_t)m * OUTW + col] = a0[j] + a1[j] + bv;
        }
    }
}

// ================= K4: addr_mega — 64 blocks x 512 thr, 4 batches/block =================
#define AB_BPB 4
__global__ __launch_bounds__(512)
void addr_mega(const float* __restrict__ rpwp, const float* __restrict__ mem_norm,
               const __hip_bfloat16* __restrict__ keys,
               const __hip_bfloat16* __restrict__ mem_b,
               const __hip_bfloat16* __restrict__ memT_b,
               const __hip_bfloat16* __restrict__ Wo_b,
               float* __restrict__ out)
{
    __shared__ float s_num[8][516];              // rows 2i=read num, 2i+1=write num (batch i); reused for gw
    __shared__ __hip_bfloat16 s_a12[16][520];    // rows 2i=read_w, 2i+1=prod (batch i); 8..15 zero
    __shared__ float s_t12[8][264];              // rows 2i=t1, 2i+1=t2 (batch i)
    __shared__ __hip_bfloat16 s_rv[16][264];     // rows i=rv batch i (i<4); 4..15 zero

    const int t = threadIdx.x;
    const int lane = t & 63;
    const int w = t >> 6;                 // wave id 0..7
    const int B0 = blockIdx.x * AB_BPB;
    const int r = lane & 15, q = lane >> 4;

    // ---- phase 1: num rows [8 real of 16] = keys[8*blk + i] . mem_b ----
    {
        const __hip_bfloat16* ap = keys + (size_t)(blockIdx.x * 8 + r) * WD + q * 8;
        bf16x8 afr[8];
        #pragma unroll
        for (int k8 = 0; k8 < 8; ++k8)
            afr[k8] = *reinterpret_cast<const bf16x8*>(ap + k8 * 32);
        for (int nt = w; nt < 32; nt += 8) {
            const __hip_bfloat16* bp = mem_b + (size_t)(nt * 16 + r) * WD + q * 8;
            f32x4 acc = {0.f,0.f,0.f,0.f};
            #pragma unroll
            for (int k8 = 0; k8 < 8; ++k8)
                acc = __builtin_amdgcn_mfma_f32_16x16x32_bf16(
                    afr[k8], *reinterpret_cast<const bf16x8*>(bp + k8 * 32), acc, 0, 0, 0);
            #pragma unroll
            for (int j = 0; j < 4; ++j) {
                int row = q * 4 + j;
                if (row < 8) s_num[row][nt * 16 + r] = acc[j];
            }
        }
    }
    __syncthreads();

    // ---- phase 2: addressing, one wave per batch (waves 0..3) ----
    float t3v = 0.f;
    float gr[8], gw8[8];
    float shr0=0,shr1=0,shr2=0,gamma_r=1, shw0=0,shw1=0,shw2=0,gamma_w=1;
    const float* pr  = rpwp + (size_t)(B0 + (w & 3)) * RW_LD;
    const float* pw2 = pr + W_OFF;
    if (w < AB_BPB) {
        // key norms
        float s2r = 0.f, s2w = 0.f;
        #pragma unroll
        for (int c = 0; c < 4; ++c) {
            float vr = pr[lane + 64 * c];  s2r += vr * vr;
            float vw = pw2[lane + 64 * c]; s2w += vw * vw;
        }
        s2r = wave_bsum(s2r); s2w = wave_bsum(s2w);
        float knr = fmaxf(sqrtf(s2r), 1e-8f), knw = fmaxf(sqrtf(s2w), 1e-8f);

        // header params (broadcast loads)
        float beta_r = softplusf(pr[WD]);
        float gate_r = sigmoidf(pr[WD + 1]);
        float r0 = pr[WD+2], r1 = pr[WD+3], r2 = pr[WD+4];
        float rmx = fmaxf(r0, fmaxf(r1, r2));
        float re0 = expf(r0-rmx), re1 = expf(r1-rmx), re2 = expf(r2-rmx);
        float rinv = 1.f / (re0+re1+re2);
        shr0 = re0*rinv; shr1 = re1*rinv; shr2 = re2*rinv;
        gamma_r = 1.f + softplusf(pr[WD + 5]);

        float beta_w = softplusf(pw2[WD]);
        float gate_w = sigmoidf(pw2[WD + 1]);
        float w0 = pw2[WD+2], w1 = pw2[WD+3], w2 = pw2[WD+4];
        float wmx = fmaxf(w0, fmaxf(w1, w2));
        float we0 = expf(w0-wmx), we1 = expf(w1-wmx), we2 = expf(w2-wmx);
        float winv = 1.f / (we0+we1+we2);
        shw0 = we0*winv; shw1 = we1*winv; shw2 = we2*winv;
        gamma_w = 1.f + softplusf(pw2[WD + 5]);

        // sims (8 slots per lane), softmax over 512
        float er[8], ew[8];
        float mr = -1e30f, mw = -1e30f;
        #pragma unroll
        for (int c = 0; c < 8; ++c) {
            int s = lane + 64 * c;
            float inv = 1.f / mem_norm[s];
            er[c] = s_num[2*w][s]   * inv / knr * beta_r;
            ew[c] = s_num[2*w+1][s] * inv / knw * beta_w;
            mr = fmaxf(mr, er[c]); mw = fmaxf(mw, ew[c]);
        }
        mr = wave_bmax(mr); mw = wave_bmax(mw);
        float sr = 0.f, sw = 0.f;
        #pragma unroll
        for (int c = 0; c < 8; ++c) {
            er[c] = expf(er[c] - mr); sr += er[c];
            ew[c] = expf(ew[c] - mw); sw += ew[c];
        }
        sr = wave_bsum(sr); sw = wave_bsum(sw);
        float irn = 1.f / sr, iwn = 1.f / sw;

        // gate (prev_w = one-hot slot 0) -> gw into s_num rows
        #pragma unroll
        for (int c = 0; c < 8; ++c) {
            int s = lane + 64 * c;
            float oh = (s == 0) ? 1.f : 0.f;
            gr[c]  = gate_r * er[c] * irn + (1.f - gate_r) * oh;
            gw8[c] = gate_w * ew[c] * iwn + (1.f - gate_w) * oh;
            s_num[2*w][s] = gr[c];
            s_num[2*w+1][s] = gw8[c];
        }
    }
    // CRITICAL fence: cross-lane LDS visibility for the shift-neighbor reads below.
    __syncthreads();
    if (w < AB_BPB) {
        // shift + sharpen
        float ssr = 0.f, ssw = 0.f;
        float spr[8], spw[8];
        #pragma unroll
        for (int c = 0; c < 8; ++c) {
            int s = lane + 64 * c;
            int sm = (s + SS - 1) & (SS - 1), sp = (s + 1) & (SS - 1);
            float vr = shr0 * s_num[2*w][sm] + shr1 * gr[c]  + shr2 * s_num[2*w][sp];
            float vw = shw0 * s_num[2*w+1][sm] + shw1 * gw8[c] + shw2 * s_num[2*w+1][sp];
            spr[c] = powf(fmaxf(vr, 0.f), gamma_r); ssr += spr[c];
            spw[c] = powf(fmaxf(vw, 0.f), gamma_w); ssw += spw[c];
        }
        ssr = wave_bsum(ssr) + 1e-6f; ssw = wave_bsum(ssw) + 1e-6f;
        float nr2 = 1.f / ssr, nw2 = 1.f / ssw;
        float t3l = 0.f;
        #pragma unroll
        for (int c = 0; c < 8; ++c) {
            int s = lane + 64 * c;
            float rf = spr[c] * nr2;
            float pd = rf * (spw[c] * nw2);
            t3l += pd;
            s_a12[2*w][s]     = __float2bfloat16(rf);
            s_a12[2*w+1][s]   = __float2bfloat16(pd);
        }
        t3v = wave_bsum(t3l);
    } else {
        // zero s_a12 pad rows 8..15 (2 rows per wave of 4..7)
        for (int rr = 8 + (w - 4); rr < 16; rr += 4)
            for (int c = lane; c < 520; c += 64)
                s_a12[rr][c] = __float2bfloat16(0.f);
    }
    __syncthreads();

    // ---- phase 3: t12 [8 real of 16 rows x 256] = s_a12 @ memT^T ----
    {
        for (int nt = w; nt < 16; nt += 8) {
            const __hip_bfloat16* bp = memT_b + (size_t)(nt * 16 + r) * SS + q * 8;
            f32x4 acc = {0.f,0.f,0.f,0.f};
            #pragma unroll
            for (int k = 0; k < SS; k += 32)
                acc = __builtin_amdgcn_mfma_f32_16x16x32_bf16(
                    *reinterpret_cast<const bf16x8*>(&s_a12[r][k + q * 8]),
                    *reinterpret_cast<const bf16x8*>(bp + k), acc, 0, 0, 0);
            #pragma unroll
            for (int j = 0; j < 4; ++j) {
                int row = q * 4 + j;
                if (row < 8) s_t12[row][nt * 16 + r] = acc[j];
            }
        }
    }
    __syncthreads();

    // ---- phase 4: rv = t1 - e*t2 + a*t3 (wave per batch); waves 4..7 zero s_rv pad ----
    if (w < AB_BPB) {
        const float* pe = rpwp + (size_t)(B0 + w) * RW_LD + W_OFF;
        #pragma unroll
        for (int c = 0; c < 4; ++c) {
            int col = lane + 64 * c;
            float t1 = s_t12[2*w][col], t2 = s_t12[2*w+1][col];
            float e = sigmoidf(pe[P_READ + col]);
            float a = tanhf(pe[P_READ + WD + col]);
            s_rv[w][col] = __float2bfloat16(t1 - e * t2 + a * t3v);
        }
    } else {
        for (int rr = 4 + (w - 4) * 3; rr < 4 + (w - 3) * 3; ++rr)
            for (int c = lane; c < 264; c += 64)
                s_rv[rr][c] = __float2bfloat16(0.f);
    }
    __syncthreads();

    // ---- phase 5: out_rv [4 rows x 512] += s_rv @ Wo_rv^T ----
    {
        bf16x8 afr[8];
        #pragma unroll
        for (int k8 = 0; k8 < 8; ++k8)
            afr[k8] = *reinterpret_cast<const bf16x8*>(&s_rv[r][k8 * 32 + q * 8]);
        for (int nt = w; nt < 32; nt += 8) {
            const __hip_bfloat16* bp = Wo_b + (size_t)(nt * 16 + r) * 1280 + 1024 + q * 8;
            f32x4 acc = {0.f,0.f,0.f,0.f};
            #pragma unroll
            for (int k8 = 0; k8 < 8; ++k8)
                acc = __builtin_amdgcn_mfma_f32_16x16x32_bf16(
                    afr[k8], *reinterpret_cast<const bf16x8*>(bp + k8 * 32), acc, 0, 0, 0);
            int col = nt * 16 + r;
            #pragma unroll
            for (int j = 0; j < 4; ++j) {
                int m = q * 4 + j;
                if (m < AB_BPB)
                    out[(size_t)(B0 + m) * OUTW + col] += acc[j];
            }
        }
    }
}

// ---------------- host launcher ----------------
extern "C" void kernel_launch(void* const* d_in, const int* in_sizes, int n_in,
                              void* d_out, int out_size, void* d_ws, size_t ws_size,
                              hipStream_t stream)
{
    const float* x       = (const float*)d_in[0];
    const float* W_ih    = (const float*)d_in[1];
    const float* b_ih    = (const float*)d_in[2];
    const float* b_hh    = (const float*)d_in[4];
    const float* W_read  = (const float*)d_in[5];
    const float* b_read  = (const float*)d_in[6];
    const float* W_write = (const float*)d_in[7];
    const float* b_write = (const float*)d_in[8];
    const float* W_out   = (const float*)d_in[9];
    const float* b_out   = (const float*)d_in[10];
    const float* mem     = (const float*)d_in[11];

    float* ws = (float*)d_ws;
    float* rpwp     = ws;                 // 270336
    float* bias_c   = ws + 270336;        // 3072
    float* bias_rw  = ws + 273408;        // 1056
    float* mem_norm = ws + 274464;        // 512
    __hip_bfloat16* bfb = (__hip_bfloat16*)(ws + 274976);
    __hip_bfloat16* x_b    = bfb;                 // 131072
    __hip_bfloat16* Wih_c  = bfb + 131072;        // 1572864
    __hip_bfloat16* Wrw_p  = bfb + 1703936;       // 1081344
    __hip_bfloat16* Wo_b   = bfb + 2785280;       // 655360
    __hip_bfloat16* mem_b  = bfb + 3440640;       // 131072
    __hip_bfloat16* memT_b = bfb + 3571712;       // 131072
    __hip_bfloat16* h_b    = bfb + 3702784;       // 262144
    __hip_bfloat16* keys   = bfb + 3964928;       // 133120 (520 rows x 256)
    float* out = (float*)d_out;

    // K1: convert/pack + mem norms + biases + keys pad
    convert_all<<<NB_CVT + SS, 256, 0, stream>>>(
        W_ih, b_ih, b_hh, W_read, b_read, W_write, b_write, W_out, x, mem,
        Wih_c, Wrw_p, Wo_b, x_b, mem_b, memT_b, bias_c, bias_rw, mem_norm, keys);
    // K2: gates GEMM + LSTM -> h_b
    gemm_gates<<<dim3(64, 16), 64, 0, stream>>>(x_b, Wih_c, bias_c, h_b);
    // K3: rpwp GEMM (+keys harvest) || out h-part GEMM
    gemm_dual<<<1568, 64, 0, stream>>>(h_b, Wrw_p, Wo_b, bias_rw, b_out, rpwp, out, keys);
    // K4: addressing + rv + out rv-part (64 blocks, 4 batches/block)
    addr_mega<<<64, 512, 0, stream>>>(rpwp, mem_norm, keys, mem_b, memT_b, Wo_b, out);
}

// Round 9
// 59.032 us; speedup vs baseline: 1.4409x; 1.3590x over previous
//
#include <hip/hip_runtime.h>
#include <hip/hip_bf16.h>
#include <math.h>

// Problem constants
#define BB   256
#define INW  512
#define HH   1024
#define OUTW 512
#define SS   512
#define WD   256
#define P_READ  262
#define P_WRITE 774
#define RW_LD   1056   // 272 (read pad) + 784 (write pad)
#define W_OFF   272

typedef __attribute__((ext_vector_type(8))) short bf16x8;
typedef __attribute__((ext_vector_type(4))) float f32x4;

__device__ __forceinline__ float sigmoidf(float x) { return 1.f / (1.f + expf(-x)); }
__device__ __forceinline__ float softplusf(float x) { return (x > 20.f) ? x : log1pf(expf(x)); }
__device__ __forceinline__ unsigned short f2b(float f) {
    union { float f; unsigned u; } c; c.f = f;
    return (unsigned short)((c.u + 0x7FFFu + ((c.u >> 16) & 1u)) >> 16);
}
__device__ __forceinline__ void st_bf4(__hip_bfloat16* d, float a, float b, float c, float e) {
    ushort4 u; u.x = f2b(a); u.y = f2b(b); u.z = f2b(c); u.w = f2b(e);
    *reinterpret_cast<ushort4*>(d) = u;
}
__device__ __forceinline__ float wave_sum(float v) {
    #pragma unroll
    for (int off = 32; off > 0; off >>= 1) v += __shfl_down(v, off, 64);
    return v;
}

// conversion segment sizes (all multiples of 4)
#define N_WIH (3072*512)
#define N_WRW (RW_LD*1024)
#define N_WO  (512*1280)
#define N_X   (256*512)
#define N_MB  (512*256)
#define N_MT  (256*512)
#define N_BIA 3072
#define N_BRW RW_LD
#define N_TOT (N_WIH+N_WRW+N_WO+N_X+N_MB+N_MT+N_BIA+N_BRW)
#define NB_CVT ((N_TOT/4 + 255) / 256)

// ================= K1: convert/pack (4-wide) + mem norms + biases =================
__global__ __launch_bounds__(256)
void convert_all(const float* __restrict__ W_ih, const float* __restrict__ b_ih,
                 const float* __restrict__ b_hh,
                 const float* __restrict__ W_read, const float* __restrict__ b_read,
                 const float* __restrict__ W_write, const float* __restrict__ b_write,
                 const float* __restrict__ W_out, const float* __restrict__ x,
                 const float* __restrict__ mem,
                 __hip_bfloat16* __restrict__ Wih_c, __hip_bfloat16* __restrict__ Wrw_p,
                 __hip_bfloat16* __restrict__ Wo_b, __hip_bfloat16* __restrict__ x_b,
                 __hip_bfloat16* __restrict__ mem_b, __hip_bfloat16* __restrict__ memT_b,
                 float* __restrict__ bias_c, float* __restrict__ bias_rw,
                 float* __restrict__ mem_norm)
{
    if (blockIdx.x >= NB_CVT) {
        __shared__ float red[4];
        int s = blockIdx.x - NB_CVT;
        float v = mem[(size_t)s * WD + threadIdx.x];
        float vv = wave_sum(v * v);
        if ((threadIdx.x & 63) == 0) red[threadIdx.x >> 6] = vv;
        __syncthreads();
        if (threadIdx.x == 0)
            mem_norm[s] = fmaxf(sqrtf(red[0] + red[1] + red[2] + red[3]), 1e-8f);
        return;
    }
    long i = ((long)blockIdx.x * 256 + threadIdx.x) * 4;
    if (i >= N_TOT) return;
    if (i < N_WIH) {
        int r = (int)(i >> 9), c = (int)(i & 511);
        int sr = r < 1024 ? r : r + 1024;    // skip f-gate rows
        float4 v = *reinterpret_cast<const float4*>(W_ih + (size_t)sr * 768 + c);
        st_bf4(Wih_c + i, v.x, v.y, v.z, v.w);
        return;
    }
    i -= N_WIH;
    if (i < N_WRW) {
        int r = (int)(i >> 10), c = (int)(i & 1023);
        float4 v = make_float4(0.f, 0.f, 0.f, 0.f);
        if (r < W_OFF) { if (r < P_READ) v = *reinterpret_cast<const float4*>(W_read + (size_t)r * 1024 + c); }
        else { int wr = r - W_OFF; if (wr < P_WRITE) v = *reinterpret_cast<const float4*>(W_write + (size_t)wr * 1024 + c); }
        st_bf4(Wrw_p + i, v.x, v.y, v.z, v.w);
        return;
    }
    i -= N_WRW;
    if (i < N_WO) {
        float4 v = *reinterpret_cast<const float4*>(W_out + i);
        st_bf4(Wo_b + i, v.x, v.y, v.z, v.w);
        return;
    }
    i -= N_WO;
    if (i < N_X) {
        float4 v = *reinterpret_cast<const float4*>(x + i);
        st_bf4(x_b + i, v.x, v.y, v.z, v.w);
        return;
    }
    i -= N_X;
    if (i < N_MB) {
        float4 v = *reinterpret_cast<const float4*>(mem + i);
        st_bf4(mem_b + i, v.x, v.y, v.z, v.w);
        return;
    }
    i -= N_MB;
    if (i < N_MT) {   // transpose gather (L2/L3-resident source)
        int w = (int)(i >> 9), s = (int)(i & 511);
        st_bf4(memT_b + i, mem[(size_t)s * 256 + w], mem[(size_t)(s + 1) * 256 + w],
               mem[(size_t)(s + 2) * 256 + w], mem[(size_t)(s + 3) * 256 + w]);
        return;
    }
    i -= N_MT;
    if (i < N_BIA) {
        #pragma unroll
        for (int u = 0; u < 4; ++u) {
            long r = i + u;
            long sr = r < 1024 ? r : r + 1024;
            bias_c[r] = b_ih[sr] + b_hh[sr];
        }
        return;
    }
    i -= N_BIA;
    {
        #pragma unroll
        for (int u = 0; u < 4; ++u) {
            long r = i + u;
            float v = 0.f;
            if (r < W_OFF) { if (r < P_READ) v = b_read[r]; }
            else { long wr = r - W_OFF; if (wr < P_WRITE) v = b_write[wr]; }
            bias_rw[r] = v;
        }
    }
}

// ================= K2: gates GEMM + LSTM -> h_b [256][1024] bf16 =================
__global__ __launch_bounds__(64)
void gemm_gates(const __hip_bfloat16* __restrict__ x_b,
                const __hip_bfloat16* __restrict__ Wih_c,
                const float* __restrict__ bias_c,
                __hip_bfloat16* __restrict__ h_b)
{
    const int l = threadIdx.x;
    const int bn = blockIdx.x * 16;
    const int bm = blockIdx.y * 16;
    const int r = l & 15, q = l >> 4;
    const __hip_bfloat16* ap = x_b + (size_t)(bm + r) * INW + q * 8;
    const __hip_bfloat16* bi = Wih_c + (size_t)(bn + r) * INW + q * 8;
    const __hip_bfloat16* bg = bi + (size_t)1024 * INW;
    const __hip_bfloat16* bo = bi + (size_t)2048 * INW;
    f32x4 ai = {0.f,0.f,0.f,0.f}, ag = ai, ao = ai;
    #pragma unroll
    for (int k = 0; k < INW; k += 32) {
        bf16x8 a = *reinterpret_cast<const bf16x8*>(ap + k);
        ai = __builtin_amdgcn_mfma_f32_16x16x32_bf16(a, *reinterpret_cast<const bf16x8*>(bi + k), ai, 0, 0, 0);
        ag = __builtin_amdgcn_mfma_f32_16x16x32_bf16(a, *reinterpret_cast<const bf16x8*>(bg + k), ag, 0, 0, 0);
        ao = __builtin_amdgcn_mfma_f32_16x16x32_bf16(a, *reinterpret_cast<const bf16x8*>(bo + k), ao, 0, 0, 0);
    }
    const int j = bn + r;
    const float bii = bias_c[j], big = bias_c[1024 + j], bio = bias_c[2048 + j];
    #pragma unroll
    for (int jj = 0; jj < 4; ++jj) {
        int b = bm + q * 4 + jj;
        float c = sigmoidf(ai[jj] + bii) * tanhf(ag[jj] + big);
        h_b[(size_t)b * HH + j] = __float2bfloat16(sigmoidf(ao[jj] + bio) * tanhf(c));
    }
}

// ================= K3: dual GEMM (rpwp + keys harvest || out h-part) =================
__global__ __launch_bounds__(64)
void gemm_dual(const __hip_bfloat16* __restrict__ h_b,
               const __hip_bfloat16* __restrict__ Wrw_p,
               const __hip_bfloat16* __restrict__ Wo_b,
               const float* __restrict__ bias_rw, const float* __restrict__ b_out,
               float* __restrict__ rpwp, float* __restrict__ out,
               __hip_bfloat16* __restrict__ keys)
{
    const int bid = blockIdx.x;
    const int lane = threadIdx.x;
    const int r = lane & 15, q = lane >> 4;
    int bm, bn, ldb;
    const __hip_bfloat16* B;
    if (bid < 1056) { int nt = bid % 66, mt = bid / 66; bm = mt * 16; bn = nt * 16; B = Wrw_p; ldb = HH; }
    else { int o = bid - 1056; int nt = o & 31, mt = o >> 5; bm = mt * 16; bn = nt * 16; B = Wo_b; ldb = 1280; }

    const __hip_bfloat16* ap = h_b + (size_t)(bm + r) * HH + q * 8;
    const __hip_bfloat16* bp = B + (size_t)(bn + r) * ldb + q * 8;
    f32x4 a0 = {0.f,0.f,0.f,0.f}, a1 = a0;
    #pragma unroll 8
    for (int k = 0; k < 512; k += 32) {
        a0 = __builtin_amdgcn_mfma_f32_16x16x32_bf16(
            *reinterpret_cast<const bf16x8*>(ap + k),
            *reinterpret_cast<const bf16x8*>(bp + k), a0, 0, 0, 0);
        a1 = __builtin_amdgcn_mfma_f32_16x16x32_bf16(
            *reinterpret_cast<const bf16x8*>(ap + 512 + k),
            *reinterpret_cast<const bf16x8*>(bp + 512 + k), a1, 0, 0, 0);
    }
    const int col = bn + r;
    if (bid < 1056) {
        const float bv = bias_rw[col];
        #pragma unroll
        for (int j = 0; j < 4; ++j) {
            int m = bm + q * 4 + j;
            float v = a0[j] + a1[j] + bv;
            rpwp[(size_t)m * RW_LD + col] = v;
            // keys: rows 0..255 = read keys, rows 256..511 = write keys
            if (col < WD)
                keys[(size_t)m * WD + col] = __float2bfloat16(v);
            else if (col >= W_OFF && col < W_OFF + WD)
                keys[(size_t)(256 + m) * WD + (col - W_OFF)] = __float2bfloat16(v);
        }
    } else {
        const float bv = b_out[col];
        #pragma unroll
        for (int j = 0; j < 4; ++j) {
            int m = bm + q * 4 + j;
            out[(size_t)m * OUTW + col] = a0[j] + a1[j] + bv;
        }
    }
}

// ================= K4a: num GEMM [512x512] = keys @ mem^T, * (1/mem_norm[col]) =================
__global__ __launch_bounds__(64)
void gemm_num(const __hip_bfloat16* __restrict__ keys,
              const __hip_bfloat16* __restrict__ mem_b,
              const float* __restrict__ mem_norm,
              float* __restrict__ numd)
{
    const int l = threadIdx.x;
    const int bn = blockIdx.x * 16;   // slot
    const int bm = blockIdx.y * 16;   // key row
    const int r = l & 15, q = l >> 4;
    const __hip_bfloat16* ap = keys + (size_t)(bm + r) * WD + q * 8;
    const __hip_bfloat16* bp = mem_b + (size_t)(bn + r) * WD + q * 8;
    f32x4 acc = {0.f,0.f,0.f,0.f};
    #pragma unroll
    for (int k = 0; k < WD; k += 32)
        acc = __builtin_amdgcn_mfma_f32_16x16x32_bf16(
            *reinterpret_cast<const bf16x8*>(ap + k),
            *reinterpret_cast<const bf16x8*>(bp + k), acc, 0, 0, 0);
    const int col = bn + r;
    const float inv = 1.f / mem_norm[col];
    #pragma unroll
    for (int j = 0; j < 4; ++j)
        numd[(size_t)(bm + q * 4 + j) * SS + col] = acc[j] * inv;
}

// ================= K4b: fused addressing (read+write) + A12 pack + t3 =================
// one block (512 threads) per batch; numd already divided by mem_norm
__device__ __forceinline__ void redpair_sum(float& a, float& b, volatile float* redA, volatile float* redB) {
    #pragma unroll
    for (int off = 32; off > 0; off >>= 1) { a += __shfl_down(a, off, 64); b += __shfl_down(b, off, 64); }
    int wid = threadIdx.x >> 6;
    __syncthreads();
    if ((threadIdx.x & 63) == 0) { redA[wid] = a; redB[wid] = b; }
    __syncthreads();
    a = redA[0]+redA[1]+redA[2]+redA[3]+redA[4]+redA[5]+redA[6]+redA[7];
    b = redB[0]+redB[1]+redB[2]+redB[3]+redB[4]+redB[5]+redB[6]+redB[7];
}
__device__ __forceinline__ void redpair_max(float& a, float& b, volatile float* redA, volatile float* redB) {
    #pragma unroll
    for (int off = 32; off > 0; off >>= 1) { a = fmaxf(a, __shfl_down(a, off, 64)); b = fmaxf(b, __shfl_down(b, off, 64)); }
    int wid = threadIdx.x >> 6;
    __syncthreads();
    if ((threadIdx.x & 63) == 0) { redA[wid] = a; redB[wid] = b; }
    __syncthreads();
    a = fmaxf(fmaxf(fmaxf(redA[0],redA[1]),fmaxf(redA[2],redA[3])),fmaxf(fmaxf(redA[4],redA[5]),fmaxf(redA[6],redA[7])));
    b = fmaxf(fmaxf(fmaxf(redB[0],redB[1]),fmaxf(redB[2],redB[3])),fmaxf(fmaxf(redB[4],redB[5]),fmaxf(redB[6],redB[7])));
}

__global__ __launch_bounds__(512)
void address_fused(const float* __restrict__ rpwp, const float* __restrict__ numd,
                   __hip_bfloat16* __restrict__ A12, float* __restrict__ t3)
{
    const int b = blockIdx.x;
    const int t = threadIdx.x;            // 0..511 = memory slot
    const float* pr = rpwp + (size_t)b * RW_LD;
    const float* pw = pr + W_OFF;

    __shared__ float redA[8], redB[8];
    __shared__ float bufr[SS], bufw[SS];

    // header params (broadcast reads)
    float beta_r  = softplusf(pr[WD]);
    float gate_r  = sigmoidf(pr[WD + 1]);
    float r0 = pr[WD+2], r1 = pr[WD+3], r2 = pr[WD+4];
    float rmx = fmaxf(r0, fmaxf(r1, r2));
    float re0 = expf(r0-rmx), re1 = expf(r1-rmx), re2 = expf(r2-rmx);
    float rinv = 1.f / (re0+re1+re2);
    float shr0 = re0*rinv, shr1 = re1*rinv, shr2 = re2*rinv;
    float gamma_r = 1.f + softplusf(pr[WD + 5]);

    float beta_w  = softplusf(pw[WD]);
    float gate_w  = sigmoidf(pw[WD + 1]);
    float w0 = pw[WD+2], w1 = pw[WD+3], w2 = pw[WD+4];
    float wmx = fmaxf(w0, fmaxf(w1, w2));
    float we0 = expf(w0-wmx), we1 = expf(w1-wmx), we2 = expf(w2-wmx);
    float winv = 1.f / (we0+we1+we2);
    float shw0 = we0*winv, shw1 = we1*winv, shw2 = we2*winv;
    float gamma_w = 1.f + softplusf(pw[WD + 5]);

    // key norms: threads 0..255 read key_r, 256..511 key_w
    {
        float kv = (t < WD) ? pr[t] : pw[t - WD];
        float vv = kv * kv;
        #pragma unroll
        for (int off = 32; off > 0; off >>= 1) vv += __shfl_down(vv, off, 64);
        int wid = t >> 6;
        if ((t & 63) == 0) redA[wid] = vv;
        __syncthreads();
    }
    float knr = fmaxf(sqrtf(redA[0]+redA[1]+redA[2]+redA[3]), 1e-8f);
    float knw = fmaxf(sqrtf(redA[4]+redA[5]+redA[6]+redA[7]), 1e-8f);
    __syncthreads();

    // cosine sims (numd pre-divided by mem_norm)
    float sim_r = numd[(size_t)b * SS + t]         / knr * beta_r;
    float sim_w = numd[(size_t)(256 + b) * SS + t] / knw * beta_w;

    // paired softmax over 512 slots
    float mr = sim_r, mw = sim_w;
    redpair_max(mr, mw, redA, redB);
    float exr = expf(sim_r - mr), exw = expf(sim_w - mw);
    float sr = exr, sw = exw;
    redpair_sum(sr, sw, redA, redB);
    float cwr = exr / sr, cww = exw / sw;

    // gate with prev_w = one-hot(0)
    float onehot = (t == 0) ? 1.f : 0.f;
    float gwr = gate_r * cwr + (1.f - gate_r) * onehot;
    float gww = gate_w * cww + (1.f - gate_w) * onehot;
    __syncthreads();
    bufr[t] = gwr; bufw[t] = gww;
    __syncthreads();

    // cyclic shift
    int tm = (t + SS - 1) & (SS - 1), tp = (t + 1) & (SS - 1);
    float swr = shr0 * bufr[tm] + shr1 * gwr + shr2 * bufr[tp];
    float sww = shw0 * bufw[tm] + shw1 * gww + shw2 * bufw[tp];

    // sharpen + normalize
    float spr = powf(fmaxf(swr, 0.f), gamma_r), spw = powf(fmaxf(sww, 0.f), gamma_w);
    float ssr = spr, ssw = spw;
    redpair_sum(ssr, ssw, redA, redB);
    float rfin = spr / (ssr + 1e-6f);
    float wfin = spw / (ssw + 1e-6f);

    // pack A12 (rows 0..255 = read_w, 256..511 = read_w*write_w) + t3
    float prod = rfin * wfin;
    A12[(size_t)b * SS + t] = __float2bfloat16(rfin);
    A12[(size_t)(256 + b) * SS + t] = __float2bfloat16(prod);
    float tp3 = prod, dummy = 0.f;
    redpair_sum(tp3, dummy, redA, redB);
    if (t == 0) t3[b] = tp3;
}

// ================= K4c: t12 GEMM + rv epilogue -> rv_b [256x256] bf16 =================
__global__ __launch_bounds__(64)
void gemm_t12rv(const __hip_bfloat16* __restrict__ A12,
                const __hip_bfloat16* __restrict__ memT_b,
                const float* __restrict__ rpwp, const float* __restrict__ t3,
                __hip_bfloat16* __restrict__ rv_b)
{
    const int l = threadIdx.x;
    const int bn = blockIdx.x * 16;   // w
    const int bm = blockIdx.y * 16;   // b
    const int r = l & 15, q = l >> 4;
    const __hip_bfloat16* a1 = A12 + (size_t)(bm + r) * SS + q * 8;
    const __hip_bfloat16* a2 = a1 + (size_t)256 * SS;
    const __hip_bfloat16* bp = memT_b + (size_t)(bn + r) * SS + q * 8;
    f32x4 acc1 = {0.f,0.f,0.f,0.f}, acc2 = acc1;
    #pragma unroll
    for (int k = 0; k < SS; k += 32) {
        bf16x8 bb = *reinterpret_cast<const bf16x8*>(bp + k);
        acc1 = __builtin_amdgcn_mfma_f32_16x16x32_bf16(*reinterpret_cast<const bf16x8*>(a1 + k), bb, acc1, 0, 0, 0);
        acc2 = __builtin_amdgcn_mfma_f32_16x16x32_bf16(*reinterpret_cast<const bf16x8*>(a2 + k), bb, acc2, 0, 0, 0);
    }
    const int w = bn + r;
    #pragma unroll
    for (int j = 0; j < 4; ++j) {
        int b = bm + q * 4 + j;
        const float* row = rpwp + (size_t)b * RW_LD;
        float e = sigmoidf(row[W_OFF + P_READ + w]);
        float a = tanhf(row[W_OFF + P_READ + WD + w]);
        float rv = acc1[j] - e * acc2[j] + a * t3[b];
        rv_b[(size_t)b * WD + w] = __float2bfloat16(rv);
    }
}

// ================= K4d: out += rv_b @ Wo_rv^T =================
__global__ __launch_bounds__(64)
void gemm_outrv(const __hip_bfloat16* __restrict__ rv_b,
                const __hip_bfloat16* __restrict__ Wo_b,
                float* __restrict__ out)
{
    const int l = threadIdx.x;
    const int bn = blockIdx.x * 16;   // out col
    const int bm = blockIdx.y * 16;   // batch
    const int r = l & 15, q = l >> 4;
    const __hip_bfloat16* ap = rv_b + (size_t)(bm + r) * WD + q * 8;
    const __hip_bfloat16* bp = Wo_b + (size_t)(bn + r) * 1280 + 1024 + q * 8;
    f32x4 acc = {0.f,0.f,0.f,0.f};
    #pragma unroll
    for (int k = 0; k < WD; k += 32)
        acc = __builtin_amdgcn_mfma_f32_16x16x32_bf16(
            *reinterpret_cast<const bf16x8*>(ap + k),
            *reinterpret_cast<const bf16x8*>(bp + k), acc, 0, 0, 0);
    const int col = bn + r;
    #pragma unroll
    for (int j = 0; j < 4; ++j) {
        int m = bm + q * 4 + j;
        out[(size_t)m * OUTW + col] += acc[j];
    }
}

// ---------------- host launcher ----------------
extern "C" void kernel_launch(void* const* d_in, const int* in_sizes, int n_in,
                              void* d_out, int out_size, void* d_ws, size_t ws_size,
                              hipStream_t stream)
{
    const float* x       = (const float*)d_in[0];
    const float* W_ih    = (const float*)d_in[1];
    const float* b_ih    = (const float*)d_in[2];
    const float* b_hh    = (const float*)d_in[4];
    const float* W_read  = (const float*)d_in[5];
    const float* b_read  = (const float*)d_in[6];
    const float* W_write = (const float*)d_in[7];
    const float* b_write = (const float*)d_in[8];
    const float* W_out   = (const float*)d_in[9];
    const float* b_out   = (const float*)d_in[10];
    const float* mem     = (const float*)d_in[11];

    float* ws = (float*)d_ws;
    float* rpwp     = ws;                 // 270336
    float* numd     = ws + 270336;        // 262144
    float* bias_c   = ws + 532480;        // 3072
    float* bias_rw  = ws + 535552;        // 1056
    float* mem_norm = ws + 536608;        // 512
    float* t3       = ws + 537120;        // 256
    __hip_bfloat16* bfb = (__hip_bfloat16*)(ws + 537376);
    __hip_bfloat16* x_b    = bfb;                 // 131072
    __hip_bfloat16* Wih_c  = bfb + 131072;        // 1572864
    __hip_bfloat16* Wrw_p  = bfb + 1703936;       // 1081344
    __hip_bfloat16* Wo_b   = bfb + 2785280;       // 655360
    __hip_bfloat16* mem_b  = bfb + 3440640;       // 131072
    __hip_bfloat16* memT_b = bfb + 3571712;       // 131072
    __hip_bfloat16* h_b    = bfb + 3702784;       // 262144
    __hip_bfloat16* keys   = bfb + 3964928;       // 131072 (rows 0..255 read, 256..511 write)
    __hip_bfloat16* A12    = bfb + 4096000;       // 262144
    __hip_bfloat16* rv_b   = bfb + 4358144;       // 65536
    float* out = (float*)d_out;

    // K1: convert/pack + mem norms + biases
    convert_all<<<NB_CVT + SS, 256, 0, stream>>>(
        W_ih, b_ih, b_hh, W_read, b_read, W_write, b_write, W_out, x, mem,
        Wih_c, Wrw_p, Wo_b, x_b, mem_b, memT_b, bias_c, bias_rw, mem_norm);
    // K2: gates GEMM + LSTM -> h_b
    gemm_gates<<<dim3(64, 16), 64, 0, stream>>>(x_b, Wih_c, bias_c, h_b);
    // K3: rpwp GEMM (+keys harvest) || out h-part GEMM
    gemm_dual<<<1568, 64, 0, stream>>>(h_b, Wrw_p, Wo_b, bias_rw, b_out, rpwp, out, keys);
    // K4a: num = keys @ mem^T (pre-divided by mem_norm)  [1024 wave-blocks]
    gemm_num<<<dim3(32, 32), 64, 0, stream>>>(keys, mem_b, mem_norm, numd);
    // K4b: addressing + A12 + t3  [256 blocks x 512]
    address_fused<<<BB, 512, 0, stream>>>(rpwp, numd, A12, t3);
    // K4c: t12 GEMM + rv -> rv_b  [256 wave-blocks]
    gemm_t12rv<<<dim3(16, 16), 64, 0, stream>>>(A12, memT_b, rpwp, t3, rv_b);
    // K4d: out += rv_b @ Wo_rv^T  [512 wave-blocks]
    gemm_outrv<<<dim3(32, 16), 64, 0, stream>>>(rv_b, Wo_b, out);
}